// Round 4
// baseline (406.666 us; speedup 1.0000x reference)
//
#include <hip/hip_runtime.h>
#include <math.h>

#define EPB 8192      // edges per block in bucket passes
#define MAXB 16384    // LDS csr staging capacity (bucket avg ~8192, sd ~90)

// ---------------- bf16 helpers (RNE) ----------------

__device__ inline float b2f(unsigned short u) {
  union { unsigned u32; float f; } c; c.u32 = ((unsigned)u) << 16; return c.f;
}
__device__ inline unsigned short f2b(float f) {
  union { float f; unsigned u; } c; c.f = f;
  unsigned r = c.u + 0x7fff + ((c.u >> 16) & 1);
  return (unsigned short)(r >> 16);
}

// ---------------- pass A0: coarse bucket histogram (bucket = dst>>8) ----------------

__global__ __launch_bounds__(256) void k_bhist(const int* __restrict__ dst, int* __restrict__ bhist,
                                               int E, int NBKT) {
  __shared__ int hist[512];
  int tid = threadIdx.x;
  int ebeg = blockIdx.x * EPB;
  int eend = min(E, ebeg + EPB);
  for (int i = tid; i < NBKT; i += 256) hist[i] = 0;
  __syncthreads();
  for (int e = ebeg + tid; e < eend; e += 256) atomicAdd(&hist[dst[e] >> 8], 1);
  __syncthreads();
  for (int i = tid; i < NBKT; i += 256) {
    int c = hist[i];
    if (c) atomicAdd(&bhist[i], c);
  }
}

// ---------------- bucket scan (single block): bbase, gcur, rowptr[N] ----------------

__global__ __launch_bounds__(256) void k_bscan(const int* __restrict__ bhist, int* __restrict__ bbase,
                                               int* __restrict__ gcur, int* __restrict__ rowptr,
                                               int E, int N, int NBKT) {
  __shared__ int a[512], c[512];
  int tid = threadIdx.x;
  int v0 = (tid < NBKT) ? bhist[tid] : 0;
  int v1 = (tid + 256 < NBKT) ? bhist[tid + 256] : 0;
  a[tid] = v0; a[tid + 256] = v1;
  __syncthreads();
  int* pin = a; int* pout = c;
  for (int st = 1; st < 512; st <<= 1) {
    pout[tid]       = pin[tid]       + ((tid >= st)       ? pin[tid - st]       : 0);
    pout[tid + 256] = pin[tid + 256] + ((tid + 256 >= st) ? pin[tid + 256 - st] : 0);
    __syncthreads();
    int* t = pin; pin = pout; pout = t;
  }
  if (tid < NBKT)       { int ex = pin[tid] - v0;       bbase[tid] = ex;       gcur[tid] = ex; }
  if (tid + 256 < NBKT) { int ex = pin[tid + 256] - v1; bbase[tid + 256] = ex; gcur[tid + 256] = ex; }
  if (tid == 0) { bbase[NBKT] = E; rowptr[N] = E; }
}

// ---------------- pass A: scatter packed (src<<8 | dstlocal) grouped by coarse bucket ----

__global__ __launch_bounds__(256) void k_bucket_scatter(const int* __restrict__ src, const int* __restrict__ dst,
                                                        int* __restrict__ gcur, unsigned* __restrict__ tmp,
                                                        int E, int NBKT) {
  __shared__ int hist[512], base[512];
  int tid = threadIdx.x;
  int ebeg = blockIdx.x * EPB;
  int eend = min(E, ebeg + EPB);
  for (int i = tid; i < NBKT; i += 256) hist[i] = 0;
  __syncthreads();
  for (int e = ebeg + tid; e < eend; e += 256) atomicAdd(&hist[dst[e] >> 8], 1);
  __syncthreads();
  for (int i = tid; i < NBKT; i += 256) {
    int c = hist[i];
    base[i] = c ? atomicAdd(&gcur[i], c) : 0;
    hist[i] = 0;
  }
  __syncthreads();
  for (int e = ebeg + tid; e < eend; e += 256) {
    int d = dst[e];
    int bkt = d >> 8;
    int o = base[bkt] + atomicAdd(&hist[bkt], 1);
    tmp[o] = ((unsigned)src[e] << 8) | (unsigned)(d & 255);
  }
}

// ---------------- pass B: per-bucket build: rowptr, dinv, csr (all LDS-local) ----------------

__global__ __launch_bounds__(256) void k_bucket_build(const unsigned* __restrict__ tmp, const int* __restrict__ bbase,
                                                      int* __restrict__ csr, int* __restrict__ rowptr,
                                                      float* __restrict__ dinv, int N) {
  int b = blockIdx.x;
  int tid = threadIdx.x;
  int node0 = b << 8;
  int nn = min(256, N - node0);
  int beg = bbase[b], end = bbase[b + 1], cnt = end - beg;
  __shared__ int h[256], off[256], cur[256];
  __shared__ int stage[MAXB];
  h[tid] = 0;
  __syncthreads();
  for (int e = beg + tid; e < end; e += 256) atomicAdd(&h[tmp[e] & 255], 1);
  __syncthreads();
  int deg = h[tid];
  off[tid] = deg;
  __syncthreads();
  for (int st = 1; st < 256; st <<= 1) {
    int t = (tid >= st) ? off[tid - st] : 0;
    __syncthreads();
    off[tid] += t;
    __syncthreads();
  }
  int excl = off[tid] - deg;
  cur[tid] = excl;
  if (tid < nn) {
    rowptr[node0 + tid] = beg + excl;
    dinv[node0 + tid] = rsqrtf((float)(deg + 1));  // +1 = self loop
  }
  __syncthreads();
  if (cnt <= MAXB) {
    for (int e = beg + tid; e < end; e += 256) {
      unsigned p = tmp[e];
      int pos = atomicAdd(&cur[p & 255], 1);
      stage[pos] = (int)(p >> 8);
    }
    __syncthreads();
    for (int k = tid; k < cnt; k += 256) csr[beg + k] = stage[k];
  } else {  // safety fallback (never taken for uniform-random dst)
    for (int e = beg + tid; e < end; e += 256) {
      unsigned p = tmp[e];
      int pos = atomicAdd(&cur[p & 255], 1);
      csr[beg + pos] = (int)(p >> 8);
    }
  }
}

// ---------------- GEMM + dinv prescale, bf16 output -----------------------------------
// SLICED: output layout [F_OUT/16][N][16] bf16 (16-feature slices, 32B rows) so the
// aggregation pass's gather working set (3.2MB) fits a per-XCD L2 (4MB).

template <int F_IN, int F_OUT, int TPN, int ROWS, bool SLICED>
__global__ __launch_bounds__(256) void k_gemm(const float* __restrict__ x, const float* __restrict__ W,
                                              const float* __restrict__ dinv, unsigned short* __restrict__ g, int N) {
  constexpr int VPT = F_OUT / TPN;
  constexpr int GROUPS = 256 / TPN;
  constexpr int NB = GROUPS * ROWS;
  __shared__ float ws[F_IN * F_OUT];
  __shared__ float xs[NB][F_IN];
  int tid = threadIdx.x;
  int base = blockIdx.x * NB;
  for (int i = tid; i < F_IN * F_OUT; i += 256) ws[i] = W[i];
  for (int i = tid; i < NB * F_IN; i += 256) {
    int r = i / F_IN, c = i - r * F_IN;
    int node = base + r;
    xs[r][c ^ (r & 31)] = (node < N) ? x[(size_t)node * F_IN + c] : 0.f;
  }
  __syncthreads();
  int fg = tid % TPN, f0 = fg * VPT;
  int ng = tid / TPN;
  int r0 = ng * ROWS;
  float acc[ROWS][VPT];
#pragma unroll
  for (int r = 0; r < ROWS; ++r)
#pragma unroll
    for (int j = 0; j < VPT; ++j) acc[r][j] = 0.f;
  for (int k = 0; k < F_IN; ++k) {
    float wv[VPT];
#pragma unroll
    for (int j = 0; j < VPT; ++j) wv[j] = ws[k * F_OUT + f0 + j];
#pragma unroll
    for (int r = 0; r < ROWS; ++r) {
      float xv = xs[r0 + r][k ^ ((r0 + r) & 31)];
#pragma unroll
      for (int j = 0; j < VPT; ++j) acc[r][j] += xv * wv[j];
    }
  }
#pragma unroll
  for (int r = 0; r < ROWS; ++r) {
    int node = base + r0 + r;
    if (node < N) {
      float dv = dinv[node];
      if constexpr (SLICED) {
#pragma unroll
        for (int j = 0; j < VPT; j += 2) {
          int fgl = f0 + j;  // (f0 multiple of 4, VPT even) -> pair stays in one slice
          size_t off = (size_t)(fgl >> 4) * ((size_t)N * 16) + (size_t)node * 16 + (fgl & 15);
          unsigned u = (unsigned)f2b(dv * acc[r][j]) | ((unsigned)f2b(dv * acc[r][j + 1]) << 16);
          *(unsigned*)(&g[off]) = u;
        }
      } else if constexpr (VPT % 2 == 0) {
#pragma unroll
        for (int j = 0; j < VPT; j += 2) {
          unsigned u = (unsigned)f2b(dv * acc[r][j]) | ((unsigned)f2b(dv * acc[r][j + 1]) << 16);
          *(unsigned*)(&g[(size_t)node * F_OUT + f0 + j]) = u;
        }
      } else {
#pragma unroll
        for (int j = 0; j < VPT; ++j) g[(size_t)node * F_OUT + f0 + j] = f2b(dv * acc[r][j]);
      }
    }
  }
}

// ---------------- sliced CSR aggregation ------------------------------------------------
// One 16-feature slice (gs = [N][16] bf16 = [N][8] u32, 3.2MB -> L2-resident).
// 8 lanes per node, 2 packed bf16 per lane; 32-bit byte offsets + uniform base
// -> 1 VALU addr op + saddr load per gather.

template <int FOUT, bool RELU>
__global__ __launch_bounds__(256) void k_aggs(const unsigned short* __restrict__ gs,
                                              const int* __restrict__ rowptr, const int* __restrict__ csr,
                                              const float* __restrict__ dinv, const float* __restrict__ bias,
                                              float* __restrict__ out, int N, int f0) {
  int t = blockIdx.x * 256 + threadIdx.x;
  int grp = t >> 3;
  if (grp >= N) return;
  unsigned subB = ((unsigned)t & 7u) << 2;
  const char* gb = (const char*)gs;
  unsigned u = *(const unsigned*)(gb + ((((unsigned)grp) << 5) + subB));
  float acc0 = __uint_as_float(u << 16);
  float acc1 = __uint_as_float(u & 0xffff0000u);
  int beg = rowptr[grp], end = rowptr[grp + 1];
  int j = beg;
  for (; j < end && (j & 3); ++j) {
    unsigned v = *(const unsigned*)(gb + ((((unsigned)csr[j]) << 5) + subB));
    acc0 += __uint_as_float(v << 16);
    acc1 += __uint_as_float(v & 0xffff0000u);
  }
  for (; j + 4 <= end; j += 4) {
    int4 ss = *(const int4*)(csr + j);
    unsigned v0 = *(const unsigned*)(gb + ((((unsigned)ss.x) << 5) + subB));
    unsigned v1 = *(const unsigned*)(gb + ((((unsigned)ss.y) << 5) + subB));
    unsigned v2 = *(const unsigned*)(gb + ((((unsigned)ss.z) << 5) + subB));
    unsigned v3 = *(const unsigned*)(gb + ((((unsigned)ss.w) << 5) + subB));
    acc0 += __uint_as_float(v0 << 16); acc1 += __uint_as_float(v0 & 0xffff0000u);
    acc0 += __uint_as_float(v1 << 16); acc1 += __uint_as_float(v1 & 0xffff0000u);
    acc0 += __uint_as_float(v2 << 16); acc1 += __uint_as_float(v2 & 0xffff0000u);
    acc0 += __uint_as_float(v3 << 16); acc1 += __uint_as_float(v3 & 0xffff0000u);
  }
  for (; j < end; ++j) {
    unsigned v = *(const unsigned*)(gb + ((((unsigned)csr[j]) << 5) + subB));
    acc0 += __uint_as_float(v << 16);
    acc1 += __uint_as_float(v & 0xffff0000u);
  }
  float dv = dinv[grp];
  int fg = f0 + (int)(subB >> 1);  // f0 + sub*2
  float r0 = fmaf(dv, acc0, bias[fg]);
  float r1 = fmaf(dv, acc1, bias[fg + 1]);
  if (RELU) { r0 = fmaxf(r0, 0.f); r1 = fmaxf(r1, 0.f); }
  *(float2*)(out + (size_t)grp * FOUT + fg) = make_float2(r0, r1);
}

// ---------------- final layer aggregation (F=2, packed 4B rows) + log_softmax --------

__global__ __launch_bounds__(256) void k_final(const unsigned* __restrict__ g2, const int* __restrict__ rowptr,
                                               const int* __restrict__ csr, const float* __restrict__ dinv,
                                               const float* __restrict__ bias, float* __restrict__ out, int N) {
  int i = blockIdx.x * 256 + threadIdx.x;
  if (i >= N) return;
  const char* gb = (const char*)g2;
  unsigned s = *(const unsigned*)(gb + (((unsigned)i) << 2));
  float a0 = __uint_as_float(s << 16), a1 = __uint_as_float(s & 0xffff0000u);
  int beg = rowptr[i], end = rowptr[i + 1];
  for (int j = beg; j < end; ++j) {
    unsigned p = *(const unsigned*)(gb + (((unsigned)csr[j]) << 2));
    a0 += __uint_as_float(p << 16);
    a1 += __uint_as_float(p & 0xffff0000u);
  }
  float dv = dinv[i];
  float v0 = fmaf(dv, a0, bias[0]);
  float v1 = fmaf(dv, a1, bias[1]);
  float m = fmaxf(v0, v1);
  float lse = m + logf(expf(v0 - m) + expf(v1 - m));
  out[2 * (size_t)i] = v0 - lse;
  out[2 * (size_t)i + 1] = v1 - lse;
}

// ---------------- launch ----------------

extern "C" void kernel_launch(void* const* d_in, const int* in_sizes, int n_in,
                              void* d_out, int out_size, void* d_ws, size_t ws_size,
                              hipStream_t stream) {
  const float* x  = (const float*)d_in[0];
  const int*   ei = (const int*)d_in[1];
  const float* W1 = (const float*)d_in[2];
  const float* b1 = (const float*)d_in[3];
  const float* W2 = (const float*)d_in[4];
  const float* b2 = (const float*)d_in[5];
  const float* W3 = (const float*)d_in[6];
  const float* b3 = (const float*)d_in[7];
  float* out = (float*)d_out;

  int N = in_sizes[0] / 128;  // 100000
  int E = in_sizes[1] / 2;    // 3200000
  const int* src = ei;        // edge_index[0]
  const int* dst = ei + E;    // edge_index[1]
  int NBKT = (N + 255) >> 8;  // 391 coarse buckets of 256 nodes

  char* w = (char*)d_ws;
  size_t off = 0;
  auto carve = [&](size_t bytes) -> char* {
    char* p = w + off;
    off = (off + bytes + 255) & ~(size_t)255;
    return p;
  };
  float* dinv   = (float*)carve((size_t)N * 4);
  int*   rowptr = (int*)carve((size_t)(N + 1) * 4);
  int*   bhist  = (int*)carve(2048);
  int*   bbase  = (int*)carve(2048 + 4);
  int*   gcur   = (int*)carve(2048);
  int*   csr    = (int*)carve((size_t)E * 4);
  size_t gsz = (size_t)N * 64 * 2;               // bf16 g buffer (sliced layout)
  if ((size_t)E * 4 > gsz) gsz = (size_t)E * 4;  // doubles as packed pair buffer
  unsigned short* gbuf = (unsigned short*)carve(gsz);
  float* hbuf   = (float*)carve((size_t)N * 64 * 4);
  unsigned* tmp = (unsigned*)gbuf;  // pair buffer dead once k_bucket_build finishes
  (void)ws_size; (void)n_in; (void)out_size;

  int nbA = (E + EPB - 1) / EPB;  // 391

  hipMemsetAsync(bhist, 0, (size_t)NBKT * 4, stream);
  k_bhist<<<nbA, 256, 0, stream>>>(dst, bhist, E, NBKT);
  k_bscan<<<1, 256, 0, stream>>>(bhist, bbase, gcur, rowptr, E, N, NBKT);
  k_bucket_scatter<<<nbA, 256, 0, stream>>>(src, dst, gcur, tmp, E, NBKT);
  k_bucket_build<<<NBKT, 256, 0, stream>>>(tmp, bbase, csr, rowptr, dinv, N);

  unsigned aggGrid = (unsigned)(((long long)N * 8 + 255) / 256);

  // layer 1: 128 -> 64, relu (4 slice passes, each gather set = 3.2MB L2-resident)
  k_gemm<128, 64, 16, 4, true><<<(N + 63) / 64, 256, 0, stream>>>(x, W1, dinv, gbuf, N);
  for (int s = 0; s < 4; ++s)
    k_aggs<64, true><<<aggGrid, 256, 0, stream>>>(gbuf + (size_t)s * N * 16, rowptr, csr, dinv, b1, hbuf, N, s * 16);
  // layer 2: 64 -> 32, relu (2 slice passes)
  k_gemm<64, 32, 8, 4, true><<<(N + 127) / 128, 256, 0, stream>>>(hbuf, W2, dinv, gbuf, N);
  for (int s = 0; s < 2; ++s)
    k_aggs<32, true><<<aggGrid, 256, 0, stream>>>(gbuf + (size_t)s * N * 16, rowptr, csr, dinv, b2, hbuf, N, s * 16);
  // layer 3: 32 -> 2, log_softmax (g2 = 400KB, L2-resident as-is)
  k_gemm<32, 2, 1, 1, false><<<(N + 255) / 256, 256, 0, stream>>>(hbuf, W3, dinv, gbuf, N);
  k_final<<<(unsigned)((N + 255) / 256), 256, 0, stream>>>((const unsigned*)gbuf, rowptr, csr, dinv, b3, out, N);
}

// Round 5
// 340.442 us; speedup vs baseline: 1.1945x; 1.1945x over previous
//
#include <hip/hip_runtime.h>
#include <math.h>

#define EPB 8192      // edges per block in bucket passes
#define MAXB 16384    // LDS csr staging capacity (bucket avg ~8192, sd ~90)

typedef __attribute__((ext_vector_type(8))) short bf16x8;
typedef __attribute__((ext_vector_type(4))) float f32x4;

// ---------------- bf16 helpers (RNE) ----------------

__device__ inline float b2f(unsigned short u) {
  union { unsigned u32; float f; } c; c.u32 = ((unsigned)u) << 16; return c.f;
}
__device__ inline unsigned short f2b(float f) {
  union { float f; unsigned u; } c; c.f = f;
  unsigned r = c.u + 0x7fff + ((c.u >> 16) & 1);
  return (unsigned short)(r >> 16);
}

// ---------------- pass A0: coarse bucket histogram (bucket = dst>>8) ----------------

__global__ __launch_bounds__(256) void k_bhist(const int* __restrict__ dst, int* __restrict__ bhist,
                                               int E, int NBKT) {
  __shared__ int hist[512];
  int tid = threadIdx.x;
  int ebeg = blockIdx.x * EPB;
  int eend = min(E, ebeg + EPB);
  for (int i = tid; i < NBKT; i += 256) hist[i] = 0;
  __syncthreads();
  for (int e = ebeg + tid; e < eend; e += 256) atomicAdd(&hist[dst[e] >> 8], 1);
  __syncthreads();
  for (int i = tid; i < NBKT; i += 256) {
    int c = hist[i];
    if (c) atomicAdd(&bhist[i], c);
  }
}

// ---------------- bucket scan (single block): bbase, gcur, rowptr[N] ----------------

__global__ __launch_bounds__(256) void k_bscan(const int* __restrict__ bhist, int* __restrict__ bbase,
                                               int* __restrict__ gcur, int* __restrict__ rowptr,
                                               int E, int N, int NBKT) {
  __shared__ int a[512], c[512];
  int tid = threadIdx.x;
  int v0 = (tid < NBKT) ? bhist[tid] : 0;
  int v1 = (tid + 256 < NBKT) ? bhist[tid + 256] : 0;
  a[tid] = v0; a[tid + 256] = v1;
  __syncthreads();
  int* pin = a; int* pout = c;
  for (int st = 1; st < 512; st <<= 1) {
    pout[tid]       = pin[tid]       + ((tid >= st)       ? pin[tid - st]       : 0);
    pout[tid + 256] = pin[tid + 256] + ((tid + 256 >= st) ? pin[tid + 256 - st] : 0);
    __syncthreads();
    int* t = pin; pin = pout; pout = t;
  }
  if (tid < NBKT)       { int ex = pin[tid] - v0;       bbase[tid] = ex;       gcur[tid] = ex; }
  if (tid + 256 < NBKT) { int ex = pin[tid + 256] - v1; bbase[tid + 256] = ex; gcur[tid + 256] = ex; }
  if (tid == 0) { bbase[NBKT] = E; rowptr[N] = E; }
}

// ---------------- pass A: scatter packed (src<<8 | dstlocal) grouped by coarse bucket ----

__global__ __launch_bounds__(256) void k_bucket_scatter(const int* __restrict__ src, const int* __restrict__ dst,
                                                        int* __restrict__ gcur, unsigned* __restrict__ tmp,
                                                        int E, int NBKT) {
  __shared__ int hist[512], base[512];
  int tid = threadIdx.x;
  int ebeg = blockIdx.x * EPB;
  int eend = min(E, ebeg + EPB);
  for (int i = tid; i < NBKT; i += 256) hist[i] = 0;
  __syncthreads();
  for (int e = ebeg + tid; e < eend; e += 256) atomicAdd(&hist[dst[e] >> 8], 1);
  __syncthreads();
  for (int i = tid; i < NBKT; i += 256) {
    int c = hist[i];
    base[i] = c ? atomicAdd(&gcur[i], c) : 0;
    hist[i] = 0;
  }
  __syncthreads();
  for (int e = ebeg + tid; e < eend; e += 256) {
    int d = dst[e];
    int bkt = d >> 8;
    int o = base[bkt] + atomicAdd(&hist[bkt], 1);
    tmp[o] = ((unsigned)src[e] << 8) | (unsigned)(d & 255);
  }
}

// ---------------- pass B: per-bucket build: rowptr, dinv, csr (all LDS-local) ----------------

__global__ __launch_bounds__(256) void k_bucket_build(const unsigned* __restrict__ tmp, const int* __restrict__ bbase,
                                                      int* __restrict__ csr, int* __restrict__ rowptr,
                                                      float* __restrict__ dinv, int N) {
  int b = blockIdx.x;
  int tid = threadIdx.x;
  int node0 = b << 8;
  int nn = min(256, N - node0);
  int beg = bbase[b], end = bbase[b + 1], cnt = end - beg;
  __shared__ int h[256], off[256], cur[256];
  __shared__ int stage[MAXB];
  h[tid] = 0;
  __syncthreads();
  for (int e = beg + tid; e < end; e += 256) atomicAdd(&h[tmp[e] & 255], 1);
  __syncthreads();
  int deg = h[tid];
  off[tid] = deg;
  __syncthreads();
  for (int st = 1; st < 256; st <<= 1) {
    int t = (tid >= st) ? off[tid - st] : 0;
    __syncthreads();
    off[tid] += t;
    __syncthreads();
  }
  int excl = off[tid] - deg;
  cur[tid] = excl;
  if (tid < nn) {
    rowptr[node0 + tid] = beg + excl;
    dinv[node0 + tid] = rsqrtf((float)(deg + 1));  // +1 = self loop
  }
  __syncthreads();
  if (cnt <= MAXB) {
    for (int e = beg + tid; e < end; e += 256) {
      unsigned p = tmp[e];
      int pos = atomicAdd(&cur[p & 255], 1);
      stage[pos] = (int)(p >> 8);
    }
    __syncthreads();
    for (int k = tid; k < cnt; k += 256) csr[beg + k] = stage[k];
  } else {  // safety fallback (never taken for uniform-random dst)
    for (int e = beg + tid; e < end; e += 256) {
      unsigned p = tmp[e];
      int pos = atomicAdd(&cur[p & 255], 1);
      csr[beg + pos] = (int)(p >> 8);
    }
  }
}

// ---------------- MFMA GEMM + dinv prescale, bf16 sliced output ------------------------
// g[f/16][node][16] = bf16(dinv[node] * (x @ W)[node][f]).
// B (W) loaded once per wave into register fragments (L2-hot); A converted f32->bf16
// in-register via v_cvt_pk_bf16_f32. A and B use the same position->k convention, so
// the HW's internal k-permutation cancels; C/D mapping col=lane&15,row=(lane>>4)*4+reg.

template <int F_IN, int F_OUT>
__global__ __launch_bounds__(256) void k_gemm_mfma(const float* __restrict__ x, const float* __restrict__ W,
                                                   const float* __restrict__ dinv, unsigned short* __restrict__ g,
                                                   int N, int NT) {
  constexpr int NKS = F_IN / 32;   // K-steps of 32
  constexpr int NCT = F_OUT / 16;  // 16-col tiles (= output slices)
  int tid = threadIdx.x;
  int w = tid >> 6, lane = tid & 63;
  int lo = lane & 15, hi = lane >> 4;

  // B fragments: frag[ct][ks], lane holds W[ks*32+hi*8+j][ct*16+lo], j=0..7
  union U8 { bf16x8 v; unsigned u[4]; };
  U8 bf[NCT][NKS];
#pragma unroll
  for (int ct = 0; ct < NCT; ++ct)
#pragma unroll
    for (int ks = 0; ks < NKS; ++ks) {
      const float* wp = W + (size_t)(ks * 32 + hi * 8) * F_OUT + ct * 16 + lo;
      float f[8];
#pragma unroll
      for (int j = 0; j < 8; ++j) f[j] = wp[(size_t)j * F_OUT];
#pragma unroll
      for (int j = 0; j < 4; ++j)
        asm("v_cvt_pk_bf16_f32 %0, %1, %2" : "=v"(bf[ct][ks].u[j]) : "v"(f[2 * j]), "v"(f[2 * j + 1]));
    }

  for (int t = blockIdx.x * 4 + w; t < NT; t += gridDim.x * 4) {
    int row0 = t << 4;
    f32x4 acc[NCT];
#pragma unroll
    for (int ct = 0; ct < NCT; ++ct) acc[ct] = (f32x4){0.f, 0.f, 0.f, 0.f};
    int rl = row0 + lo; if (rl >= N) rl = N - 1;  // clamp (tail-safe; exact fit at N=100000)
    const float* xrow = x + (size_t)rl * F_IN;
#pragma unroll
    for (int ks = 0; ks < NKS; ++ks) {
      const float* xp = xrow + ks * 32 + hi * 8;
      float4 a0 = *(const float4*)xp;
      float4 a1 = *(const float4*)(xp + 4);
      U8 af;
      asm("v_cvt_pk_bf16_f32 %0, %1, %2" : "=v"(af.u[0]) : "v"(a0.x), "v"(a0.y));
      asm("v_cvt_pk_bf16_f32 %0, %1, %2" : "=v"(af.u[1]) : "v"(a0.z), "v"(a0.w));
      asm("v_cvt_pk_bf16_f32 %0, %1, %2" : "=v"(af.u[2]) : "v"(a1.x), "v"(a1.y));
      asm("v_cvt_pk_bf16_f32 %0, %1, %2" : "=v"(af.u[3]) : "v"(a1.z), "v"(a1.w));
#pragma unroll
      for (int ct = 0; ct < NCT; ++ct)
        acc[ct] = __builtin_amdgcn_mfma_f32_16x16x32_bf16(af.v, bf[ct][ks].v, acc[ct], 0, 0, 0);
    }
    float dvv[4];
    if (row0 + 16 <= N) {
      float4 d4 = *(const float4*)(dinv + row0 + (hi << 2));
      dvv[0] = d4.x; dvv[1] = d4.y; dvv[2] = d4.z; dvv[3] = d4.w;
    } else {
#pragma unroll
      for (int j = 0; j < 4; ++j) { int r = row0 + (hi << 2) + j; dvv[j] = dinv[r < N ? r : N - 1]; }
    }
#pragma unroll
    for (int ct = 0; ct < NCT; ++ct) {
      size_t sb = (size_t)ct * ((size_t)N * 16);
#pragma unroll
      for (int j = 0; j < 4; ++j) {
        int row = row0 + (hi << 2) + j;
        if (row < N) g[sb + (size_t)row * 16 + lo] = f2b(dvv[j] * acc[ct][j]);
      }
    }
  }
}

// ---------------- vector GEMM (layer 3 only: 32 -> 2) ----------------------------------

template <int F_IN, int F_OUT, int TPN, int ROWS>
__global__ __launch_bounds__(256) void k_gemm(const float* __restrict__ x, const float* __restrict__ W,
                                              const float* __restrict__ dinv, unsigned short* __restrict__ g, int N) {
  constexpr int VPT = F_OUT / TPN;
  constexpr int GROUPS = 256 / TPN;
  constexpr int NB = GROUPS * ROWS;
  __shared__ float ws[F_IN * F_OUT];
  __shared__ float xs[NB][F_IN];
  int tid = threadIdx.x;
  int base = blockIdx.x * NB;
  for (int i = tid; i < F_IN * F_OUT; i += 256) ws[i] = W[i];
  for (int i = tid; i < NB * F_IN; i += 256) {
    int r = i / F_IN, c = i - r * F_IN;
    int node = base + r;
    xs[r][c ^ (r & 31)] = (node < N) ? x[(size_t)node * F_IN + c] : 0.f;
  }
  __syncthreads();
  int fg = tid % TPN, f0 = fg * VPT;
  int ng = tid / TPN;
  int r0 = ng * ROWS;
  float acc[ROWS][VPT];
#pragma unroll
  for (int r = 0; r < ROWS; ++r)
#pragma unroll
    for (int j = 0; j < VPT; ++j) acc[r][j] = 0.f;
  for (int k = 0; k < F_IN; ++k) {
    float wv[VPT];
#pragma unroll
    for (int j = 0; j < VPT; ++j) wv[j] = ws[k * F_OUT + f0 + j];
#pragma unroll
    for (int r = 0; r < ROWS; ++r) {
      float xv = xs[r0 + r][k ^ ((r0 + r) & 31)];
#pragma unroll
      for (int j = 0; j < VPT; ++j) acc[r][j] += xv * wv[j];
    }
  }
#pragma unroll
  for (int r = 0; r < ROWS; ++r) {
    int node = base + r0 + r;
    if (node < N) {
      float dv = dinv[node];
#pragma unroll
      for (int j = 0; j < VPT; ++j) g[(size_t)node * F_OUT + f0 + j] = f2b(dv * acc[r][j]);
    }
  }
}

// ---------------- sliced CSR aggregation ------------------------------------------------

template <int FOUT, bool RELU>
__global__ __launch_bounds__(256) void k_aggs(const unsigned short* __restrict__ gs,
                                              const int* __restrict__ rowptr, const int* __restrict__ csr,
                                              const float* __restrict__ dinv, const float* __restrict__ bias,
                                              float* __restrict__ out, int N, int f0) {
  int t = blockIdx.x * 256 + threadIdx.x;
  int grp = t >> 3;
  if (grp >= N) return;
  unsigned subB = ((unsigned)t & 7u) << 2;
  const char* gb = (const char*)gs;
  unsigned u = *(const unsigned*)(gb + ((((unsigned)grp) << 5) + subB));
  float acc0 = __uint_as_float(u << 16);
  float acc1 = __uint_as_float(u & 0xffff0000u);
  int beg = rowptr[grp], end = rowptr[grp + 1];
  int j = beg;
  for (; j < end && (j & 3); ++j) {
    unsigned v = *(const unsigned*)(gb + ((((unsigned)csr[j]) << 5) + subB));
    acc0 += __uint_as_float(v << 16);
    acc1 += __uint_as_float(v & 0xffff0000u);
  }
  for (; j + 4 <= end; j += 4) {
    int4 ss = *(const int4*)(csr + j);
    unsigned v0 = *(const unsigned*)(gb + ((((unsigned)ss.x) << 5) + subB));
    unsigned v1 = *(const unsigned*)(gb + ((((unsigned)ss.y) << 5) + subB));
    unsigned v2 = *(const unsigned*)(gb + ((((unsigned)ss.z) << 5) + subB));
    unsigned v3 = *(const unsigned*)(gb + ((((unsigned)ss.w) << 5) + subB));
    acc0 += __uint_as_float(v0 << 16); acc1 += __uint_as_float(v0 & 0xffff0000u);
    acc0 += __uint_as_float(v1 << 16); acc1 += __uint_as_float(v1 & 0xffff0000u);
    acc0 += __uint_as_float(v2 << 16); acc1 += __uint_as_float(v2 & 0xffff0000u);
    acc0 += __uint_as_float(v3 << 16); acc1 += __uint_as_float(v3 & 0xffff0000u);
  }
  for (; j < end; ++j) {
    unsigned v = *(const unsigned*)(gb + ((((unsigned)csr[j]) << 5) + subB));
    acc0 += __uint_as_float(v << 16);
    acc1 += __uint_as_float(v & 0xffff0000u);
  }
  float dv = dinv[grp];
  int fg = f0 + (int)(subB >> 1);
  float r0 = fmaf(dv, acc0, bias[fg]);
  float r1 = fmaf(dv, acc1, bias[fg + 1]);
  if (RELU) { r0 = fmaxf(r0, 0.f); r1 = fmaxf(r1, 0.f); }
  *(float2*)(out + (size_t)grp * FOUT + fg) = make_float2(r0, r1);
}

// ---------------- final layer aggregation (F=2, packed 4B rows) + log_softmax --------

__global__ __launch_bounds__(256) void k_final(const unsigned* __restrict__ g2, const int* __restrict__ rowptr,
                                               const int* __restrict__ csr, const float* __restrict__ dinv,
                                               const float* __restrict__ bias, float* __restrict__ out, int N) {
  int i = blockIdx.x * 256 + threadIdx.x;
  if (i >= N) return;
  const char* gb = (const char*)g2;
  unsigned s = *(const unsigned*)(gb + (((unsigned)i) << 2));
  float a0 = __uint_as_float(s << 16), a1 = __uint_as_float(s & 0xffff0000u);
  int beg = rowptr[i], end = rowptr[i + 1];
  for (int j = beg; j < end; ++j) {
    unsigned p = *(const unsigned*)(gb + (((unsigned)csr[j]) << 2));
    a0 += __uint_as_float(p << 16);
    a1 += __uint_as_float(p & 0xffff0000u);
  }
  float dv = dinv[i];
  float v0 = fmaf(dv, a0, bias[0]);
  float v1 = fmaf(dv, a1, bias[1]);
  float m = fmaxf(v0, v1);
  float lse = m + logf(expf(v0 - m) + expf(v1 - m));
  out[2 * (size_t)i] = v0 - lse;
  out[2 * (size_t)i + 1] = v1 - lse;
}

// ---------------- launch ----------------

extern "C" void kernel_launch(void* const* d_in, const int* in_sizes, int n_in,
                              void* d_out, int out_size, void* d_ws, size_t ws_size,
                              hipStream_t stream) {
  const float* x  = (const float*)d_in[0];
  const int*   ei = (const int*)d_in[1];
  const float* W1 = (const float*)d_in[2];
  const float* b1 = (const float*)d_in[3];
  const float* W2 = (const float*)d_in[4];
  const float* b2 = (const float*)d_in[5];
  const float* W3 = (const float*)d_in[6];
  const float* b3 = (const float*)d_in[7];
  float* out = (float*)d_out;

  int N = in_sizes[0] / 128;  // 100000
  int E = in_sizes[1] / 2;    // 3200000
  const int* src = ei;        // edge_index[0]
  const int* dst = ei + E;    // edge_index[1]
  int NBKT = (N + 255) >> 8;  // 391 coarse buckets of 256 nodes
  int NT = (N + 15) / 16;     // 6250 row-tiles

  char* w = (char*)d_ws;
  size_t off = 0;
  auto carve = [&](size_t bytes) -> char* {
    char* p = w + off;
    off = (off + bytes + 255) & ~(size_t)255;
    return p;
  };
  float* dinv   = (float*)carve((size_t)N * 4);
  int*   rowptr = (int*)carve((size_t)(N + 1) * 4);
  int*   bhist  = (int*)carve(2048);
  int*   bbase  = (int*)carve(2048 + 4);
  int*   gcur   = (int*)carve(2048);
  int*   csr    = (int*)carve((size_t)E * 4);
  size_t gsz = (size_t)N * 64 * 2;               // bf16 g buffer (sliced layout)
  if ((size_t)E * 4 > gsz) gsz = (size_t)E * 4;  // doubles as packed pair buffer
  unsigned short* gbuf = (unsigned short*)carve(gsz);
  float* hbuf   = (float*)carve((size_t)N * 64 * 4);
  unsigned* tmp = (unsigned*)gbuf;  // pair buffer dead once k_bucket_build finishes
  (void)ws_size; (void)n_in; (void)out_size;

  int nbA = (E + EPB - 1) / EPB;  // 391

  hipMemsetAsync(bhist, 0, (size_t)NBKT * 4, stream);
  k_bhist<<<nbA, 256, 0, stream>>>(dst, bhist, E, NBKT);
  k_bscan<<<1, 256, 0, stream>>>(bhist, bbase, gcur, rowptr, E, N, NBKT);
  k_bucket_scatter<<<nbA, 256, 0, stream>>>(src, dst, gcur, tmp, E, NBKT);
  k_bucket_build<<<NBKT, 256, 0, stream>>>(tmp, bbase, csr, rowptr, dinv, N);

  unsigned aggGrid = (unsigned)(((long long)N * 8 + 255) / 256);

  // layer 1: 128 -> 64 MFMA, relu (4 slice passes, gather set 3.2MB L2-resident)
  k_gemm_mfma<128, 64><<<782, 256, 0, stream>>>(x, W1, dinv, gbuf, N, NT);
  for (int s = 0; s < 4; ++s)
    k_aggs<64, true><<<aggGrid, 256, 0, stream>>>(gbuf + (size_t)s * N * 16, rowptr, csr, dinv, b1, hbuf, N, s * 16);
  // layer 2: 64 -> 32 MFMA, relu (2 slice passes)
  k_gemm_mfma<64, 32><<<782, 256, 0, stream>>>(hbuf, W2, dinv, gbuf, N, NT);
  for (int s = 0; s < 2; ++s)
    k_aggs<32, true><<<aggGrid, 256, 0, stream>>>(gbuf + (size_t)s * N * 16, rowptr, csr, dinv, b2, hbuf, N, s * 16);
  // layer 3: 32 -> 2 vector, log_softmax (g2 = 400KB, L2-resident as-is)
  k_gemm<32, 2, 1, 1><<<(N + 255) / 256, 256, 0, stream>>>(hbuf, W3, dinv, gbuf, N);
  k_final<<<(unsigned)((N + 255) / 256), 256, 0, stream>>>((const unsigned*)gbuf, rowptr, csr, dinv, b3, out, N);
}